// Round 6
// baseline (786.513 us; speedup 1.0000x reference)
//
#include <hip/hip_runtime.h>
#include <hip/hip_cooperative_groups.h>
#include <math.h>

namespace cg = cooperative_groups;

#define IN_C 128
#define CSR_BLOCKS 1024  // 4 blocks/CU x 256 CU; 16 waves/CU for atomic latency hiding

typedef short short8 __attribute__((ext_vector_type(8)));
typedef float floatx4 __attribute__((ext_vector_type(4)));

static __device__ __forceinline__ unsigned short f2bf(float f) {
    unsigned int u = __float_as_uint(f);
    u += 0x7fffu + ((u >> 16) & 1u);  // RNE
    return (unsigned short)(u >> 16);
}

// ---------------- K1: fused CSR builder (cooperative, 1024 blocks) ----------------
// P1 : zero packed histogram; blocks 0..63 run GRU weight evolution (2 rows each)
// P2 : packed histogram pk[c] += (1<<32)|fix24(w); returned high word = edge rank
// P3 : scan counts -> rowptr; dinv from packed weight sum
// P4 : placement with pos = rowptr[col] + rank  (NO atomics)
__global__ __launch_bounds__(256, 4) void build_csr(
        const int* __restrict__ rowi, const int* __restrict__ coli,
        const float* __restrict__ ew,
        const float* __restrict__ W0, const float* __restrict__ Wih,
        const float* __restrict__ Whh, const float* __restrict__ bih,
        const float* __restrict__ bhh,
        unsigned long long* __restrict__ pk, float* __restrict__ dinv,
        int* __restrict__ rowptr, unsigned int* __restrict__ rank,
        int* __restrict__ partials, uint2* __restrict__ edge_sn,
        unsigned short* __restrict__ Wbt, int n, int E, int NB) {
    cg::grid_group grid = cg::this_grid();
    const int t = threadIdx.x;
    const int b = blockIdx.x;
    const int G = gridDim.x;
    const int tid = b * 256 + t;
    const int T = G * 256;
    __shared__ int s[256];
    __shared__ float w0row[2][IN_C];
    __shared__ int carry_s;

    // ---- P1: zero packed histogram ----
    for (int i = tid; i < n; i += T) pk[i] = 0ull;

    // ---- P1b: GRU weight evolution (blocks 0..63, 2 rows of W0 each) ----
    if (b < 64) {
        const int r2 = t >> 7;       // 0 or 1
        const int j = t & 127;
        const int i = b * 2 + r2;
        w0row[r2][j] = W0[i * IN_C + j];
        __syncthreads();
        float ir = bih[j], iz = bih[j + IN_C], inn = bih[j + 2 * IN_C];
        float hr = bhh[j], hz = bhh[j + IN_C], hnn = bhh[j + 2 * IN_C];
        const float* wr = &Wih[(size_t)j * IN_C];
        const float* wz = &Wih[(size_t)(j + IN_C) * IN_C];
        const float* wn = &Wih[(size_t)(j + 2 * IN_C) * IN_C];
        const float* ur = &Whh[(size_t)j * IN_C];
        const float* uz = &Whh[(size_t)(j + IN_C) * IN_C];
        const float* un = &Whh[(size_t)(j + 2 * IN_C) * IN_C];
        #pragma unroll 4
        for (int k = 0; k < IN_C; ++k) {
            const float a = w0row[r2][k];
            ir = fmaf(a, wr[k], ir); iz = fmaf(a, wz[k], iz); inn = fmaf(a, wn[k], inn);
            hr = fmaf(a, ur[k], hr); hz = fmaf(a, uz[k], hz); hnn = fmaf(a, un[k], hnn);
        }
        const float r = 1.0f / (1.0f + expf(-(ir + hr)));
        const float z = 1.0f / (1.0f + expf(-(iz + hz)));
        const float cand = tanhf(inn + r * hnn);
        Wbt[j * IN_C + i] = f2bf((1.0f - z) * cand + z * w0row[r2][j]);  // W[i][j] -> Wbt[j][i]
        __syncthreads();
    }
    grid.sync();

    // ---- P2: packed histogram with rank capture, 4 edges/thread iteration ----
    for (int e0 = tid * 4; e0 < E; e0 += T * 4) {
        if (e0 + 3 < E) {
            const int4 c4 = *(const int4*)&coli[e0];
            const float4 w4 = *(const float4*)&ew[e0];
            const unsigned long long o0 = atomicAdd(&pk[c4.x], (1ull << 32) | (unsigned long long)(unsigned int)(w4.x * 16777216.0f));
            const unsigned long long o1 = atomicAdd(&pk[c4.y], (1ull << 32) | (unsigned long long)(unsigned int)(w4.y * 16777216.0f));
            const unsigned long long o2 = atomicAdd(&pk[c4.z], (1ull << 32) | (unsigned long long)(unsigned int)(w4.z * 16777216.0f));
            const unsigned long long o3 = atomicAdd(&pk[c4.w], (1ull << 32) | (unsigned long long)(unsigned int)(w4.w * 16777216.0f));
            uint4 rk;
            rk.x = (unsigned int)(o0 >> 32); rk.y = (unsigned int)(o1 >> 32);
            rk.z = (unsigned int)(o2 >> 32); rk.w = (unsigned int)(o3 >> 32);
            *(uint4*)&rank[e0] = rk;
        } else {
            for (int e = e0; e < E; ++e) {
                const unsigned long long o = atomicAdd(&pk[coli[e]], (1ull << 32) | (unsigned long long)(unsigned int)(ew[e] * 16777216.0f));
                rank[e] = (unsigned int)(o >> 32);
            }
        }
    }
    grid.sync();

    // ---- P3a: per-chunk scan of counts; dinv from wsum ----
    for (int c = b; c < NB; c += G) {
        __syncthreads();
        const int i = c * 256 + t;
        unsigned long long pv = (i < n) ? pk[i] : 0ull;
        const int cnt = (int)(pv >> 32);
        if (i < n)
            dinv[i] = rsqrtf((float)(unsigned int)(pv & 0xffffffffull) * (1.0f / 16777216.0f) + 1.0f);
        s[t] = cnt;
        __syncthreads();
        #pragma unroll
        for (int off = 1; off < 256; off <<= 1) {
            const int v = (t >= off) ? s[t - off] : 0;
            __syncthreads();
            s[t] += v;
            __syncthreads();
        }
        if (i < n) rowptr[i] = (t == 0) ? 0 : s[t - 1];
        if (t == 255) partials[c] = s[255];
    }
    grid.sync();

    // ---- P3b: single-block scan of partials ----
    if (b == 0) {
        if (t == 0) carry_s = 0;
        for (int tile = 0; tile * 256 < NB; ++tile) {
            __syncthreads();
            const int base_carry = carry_s;
            const int idx = tile * 256 + t;
            const int v = (idx < NB) ? partials[idx] : 0;
            s[t] = v;
            __syncthreads();
            #pragma unroll
            for (int off = 1; off < 256; off <<= 1) {
                const int u = (t >= off) ? s[t - off] : 0;
                __syncthreads();
                s[t] += u;
                __syncthreads();
            }
            if (idx < NB) partials[idx] = base_carry + s[t] - v;
            if (t == 255) carry_s = base_carry + s[255];
        }
        __syncthreads();
        if (t == 0) rowptr[n] = E;
    }
    grid.sync();

    // ---- P3c: add block offsets to rowptr ----
    for (int c = b; c < NB; c += G) {
        const int i = c * 256 + t;
        if (i < n) rowptr[i] += partials[c];
    }
    grid.sync();

    // ---- P4: placement via rowptr + rank (no atomics) ----
    for (int e0 = tid * 4; e0 < E; e0 += T * 4) {
        if (e0 + 3 < E) {
            const int4 r4 = *(const int4*)&rowi[e0];
            const int4 c4 = *(const int4*)&coli[e0];
            const float4 w4 = *(const float4*)&ew[e0];
            const uint4 rk = *(const uint4*)&rank[e0];
            edge_sn[rowptr[c4.x] + rk.x] = make_uint2((unsigned)r4.x, __float_as_uint(dinv[r4.x] * w4.x * dinv[c4.x]));
            edge_sn[rowptr[c4.y] + rk.y] = make_uint2((unsigned)r4.y, __float_as_uint(dinv[r4.y] * w4.y * dinv[c4.y]));
            edge_sn[rowptr[c4.z] + rk.z] = make_uint2((unsigned)r4.z, __float_as_uint(dinv[r4.z] * w4.z * dinv[c4.z]));
            edge_sn[rowptr[c4.w] + rk.w] = make_uint2((unsigned)r4.w, __float_as_uint(dinv[r4.w] * w4.w * dinv[c4.w]));
        } else {
            for (int e = e0; e < E; ++e) {
                const int r = rowi[e], c = coli[e];
                edge_sn[rowptr[c] + rank[e]] = make_uint2((unsigned)r, __float_as_uint(dinv[r] * ew[e] * dinv[c]));
            }
        }
    }
}

// ---------------- K2: h = bf16(x @ W) via MFMA ----------------
#define ALD 136  // 128 + 8 shorts pad
__global__ __launch_bounds__(256) void gemm_bf16(const float* __restrict__ x,
                                                 const unsigned short* __restrict__ Wbt,
                                                 unsigned short* __restrict__ hb, int n) {
    __shared__ unsigned short As[128 * ALD];
    __shared__ unsigned short Ws[128 * ALD];
    const int t = threadIdx.x;
    const size_t row0 = (size_t)blockIdx.x * 128;

    for (int idx = t; idx < 2048; idx += 256) {
        const int nn = idx >> 4, k8 = (idx & 15) * 8;
        *(uint4*)&Ws[nn * ALD + k8] = *(const uint4*)&Wbt[nn * IN_C + k8];
    }
    for (int idx = t; idx < 4096; idx += 256) {
        const int r = idx >> 5, c4 = (idx & 31) * 4;
        size_t row = row0 + r;
        if (row >= (size_t)n) row = (size_t)n - 1;
        const float4 v = *(const float4*)&x[row * IN_C + c4];
        ushort4 bb;
        bb.x = f2bf(v.x); bb.y = f2bf(v.y); bb.z = f2bf(v.z); bb.w = f2bf(v.w);
        *(ushort4*)&As[r * ALD + c4] = bb;
    }
    __syncthreads();

    const int w = t >> 6, lane = t & 63, ln = lane & 15, quad = lane >> 4;
    floatx4 acc[2][8];
    #pragma unroll
    for (int mt = 0; mt < 2; ++mt)
        #pragma unroll
        for (int nt = 0; nt < 8; ++nt)
            acc[mt][nt] = (floatx4){0.f, 0.f, 0.f, 0.f};

    #pragma unroll
    for (int k0 = 0; k0 < 128; k0 += 32) {
        const short8 a0 = *(const short8*)&As[(w * 32 + ln) * ALD + k0 + quad * 8];
        const short8 a1 = *(const short8*)&As[(w * 32 + 16 + ln) * ALD + k0 + quad * 8];
        #pragma unroll
        for (int nt = 0; nt < 8; ++nt) {
            const short8 bb = *(const short8*)&Ws[(nt * 16 + ln) * ALD + k0 + quad * 8];
            acc[0][nt] = __builtin_amdgcn_mfma_f32_16x16x32_bf16(a0, bb, acc[0][nt], 0, 0, 0);
            acc[1][nt] = __builtin_amdgcn_mfma_f32_16x16x32_bf16(a1, bb, acc[1][nt], 0, 0, 0);
        }
    }

    #pragma unroll
    for (int mt = 0; mt < 2; ++mt) {
        #pragma unroll
        for (int reg = 0; reg < 4; ++reg) {
            const size_t row = row0 + w * 32 + mt * 16 + quad * 4 + reg;
            if (row < (size_t)n) {
                #pragma unroll
                for (int nt = 0; nt < 8; ++nt)
                    hb[row * IN_C + nt * 16 + ln] = f2bf(acc[mt][nt][reg]);
            }
        }
    }
}

// ---------------- K3: fused gather + self-loop + ReLU + classifier ----------------
__global__ __launch_bounds__(256) void gather_classify(
        const unsigned short* __restrict__ hb, const float* __restrict__ dinv,
        const int* __restrict__ rowptr, const uint2* __restrict__ edge_sn,
        const float* __restrict__ cls_w, const float* __restrict__ cls_b,
        float* __restrict__ out, int n) {
    const int wid = __builtin_amdgcn_readfirstlane((blockIdx.x * blockDim.x + threadIdx.x) >> 6);
    const int lane = threadIdx.x & 63;
    if (wid >= n) return;

    const float dv = dinv[wid];
    unsigned int hv = *(const unsigned int*)&hb[(size_t)wid * IN_C + 2 * lane];
    float ax = dv * dv * __uint_as_float(hv << 16);
    float ay = dv * dv * __uint_as_float(hv & 0xffff0000u);

    const int e0 = rowptr[wid];
    const int e1 = rowptr[wid + 1];
    const int e1m1 = e1 - 1;
    for (int e = e0; e < e1; e += 8) {
        uint2 p[8];
        #pragma unroll
        for (int i = 0; i < 8; ++i) {
            const int idx = (e + i < e1) ? (e + i) : e1m1;
            p[i] = edge_sn[idx];
        }
        unsigned int hr[8];
        #pragma unroll
        for (int i = 0; i < 8; ++i)
            hr[i] = *(const unsigned int*)&hb[(size_t)p[i].x * IN_C + 2 * lane];
        #pragma unroll
        for (int i = 0; i < 8; ++i) {
            const float nm = (e + i < e1) ? __uint_as_float(p[i].y) : 0.0f;
            ax = fmaf(nm, __uint_as_float(hr[i] << 16), ax);
            ay = fmaf(nm, __uint_as_float(hr[i] & 0xffff0000u), ay);
        }
    }

    const float2 wv = *(const float2*)&cls_w[2 * lane];
    float sum = wv.x * fmaxf(ax, 0.0f) + wv.y * fmaxf(ay, 0.0f);
    #pragma unroll
    for (int off = 32; off > 0; off >>= 1) sum += __shfl_down(sum, off);
    if (lane == 0) out[wid] = sum + cls_b[0];
}

extern "C" void kernel_launch(void* const* d_in, const int* in_sizes, int n_in,
                              void* d_out, int out_size, void* d_ws, size_t ws_size,
                              hipStream_t stream) {
    const float* x    = (const float*)d_in[0];
    const int*   eidx = (const int*)d_in[1];   // [2, E] int32
    const float* ew   = (const float*)d_in[2];
    const float* W0   = (const float*)d_in[3];
    const float* Wih  = (const float*)d_in[4];
    const float* Whh  = (const float*)d_in[5];
    const float* bih  = (const float*)d_in[6];
    const float* bhh  = (const float*)d_in[7];
    const float* clsw = (const float*)d_in[8];
    const float* clsb = (const float*)d_in[9];
    float* out = (float*)d_out;

    int n = in_sizes[0] / IN_C;   // 100000
    int E = in_sizes[2];          // 600000
    const int* rowi = eidx;
    const int* coli = eidx + E;
    int NB = (n + 255) / 256;     // <= 512

    // workspace layout (4-byte units from base)
    int* base = (int*)d_ws;
    unsigned long long* pk = (unsigned long long*)base;          // n u64 (8B aligned)
    float* dinv   = (float*)(base + 2 * (size_t)n);              // n
    int* rowptr   = base + 3 * (size_t)n;                        // n+1
    int* partials = base + 4 * (size_t)n + 1;                    // 512
    unsigned int* rank = (unsigned int*)(base + 4 * (size_t)n + 513);  // E
    size_t off = 4 * (size_t)n + 513 + (size_t)E;
    off = (off + 3) & ~(size_t)3;                                // 16B align
    uint2* edge_sn = (uint2*)(base + off);                       // E uint2
    unsigned short* Wbt = (unsigned short*)(base + off + 2 * (size_t)E);  // 16384 bf16
    unsigned short* hb  = Wbt + 16384;                           // n*128 bf16

    // 1. fused CSR build (cooperative, 1024 blocks)
    void* args[] = { (void*)&rowi, (void*)&coli, (void*)&ew, (void*)&W0, (void*)&Wih,
                     (void*)&Whh, (void*)&bih, (void*)&bhh, (void*)&pk, (void*)&dinv,
                     (void*)&rowptr, (void*)&rank, (void*)&partials, (void*)&edge_sn,
                     (void*)&Wbt, (void*)&n, (void*)&E, (void*)&NB };
    hipLaunchCooperativeKernel((void*)build_csr, dim3(CSR_BLOCKS), dim3(256), args, 0, stream);

    // 2. h = bf16(x @ W) via MFMA
    gemm_bf16<<<dim3((n + 127) / 128), dim3(256), 0, stream>>>(x, Wbt, hb, n);

    // 3. fused gather + ReLU + classifier
    gather_classify<<<dim3((n + 3) / 4), dim3(256), 0, stream>>>(hb, dinv, rowptr, edge_sn,
                                                                 clsw, clsb, out, n);
}

// Round 7
// 223.356 us; speedup vs baseline: 3.5213x; 3.5213x over previous
//
#include <hip/hip_runtime.h>
#include <math.h>

#define IN_C 128

typedef short short8 __attribute__((ext_vector_type(8)));
typedef float floatx4 __attribute__((ext_vector_type(4)));

static __device__ __forceinline__ unsigned short f2bf(float f) {
    unsigned int u = __float_as_uint(f);
    u += 0x7fffu + ((u >> 16) & 1u);  // RNE
    return (unsigned short)(u >> 16);
}

// ---------------- K1: EvolveGCNO GRU step on W0 -> Wbt (bf16, transposed) ----------------
__global__ void evolve_w(const float* __restrict__ W0,
                         const float* __restrict__ Wih,
                         const float* __restrict__ Whh,
                         const float* __restrict__ bih,
                         const float* __restrict__ bhh,
                         unsigned short* __restrict__ Wbt) {
    __shared__ float w0row[IN_C];
    const int i = blockIdx.x;   // row of W0
    const int j = threadIdx.x;  // col of W
    w0row[j] = W0[i * IN_C + j];
    __syncthreads();

    float ir = bih[j], iz = bih[j + IN_C], inn = bih[j + 2 * IN_C];
    float hr = bhh[j], hz = bhh[j + IN_C], hnn = bhh[j + 2 * IN_C];
    const float* wr = &Wih[(size_t)j * IN_C];
    const float* wz = &Wih[(size_t)(j + IN_C) * IN_C];
    const float* wn = &Wih[(size_t)(j + 2 * IN_C) * IN_C];
    const float* ur = &Whh[(size_t)j * IN_C];
    const float* uz = &Whh[(size_t)(j + IN_C) * IN_C];
    const float* un = &Whh[(size_t)(j + 2 * IN_C) * IN_C];
    #pragma unroll 4
    for (int k = 0; k < IN_C; ++k) {
        const float a = w0row[k];
        ir = fmaf(a, wr[k], ir); iz = fmaf(a, wz[k], iz); inn = fmaf(a, wn[k], inn);
        hr = fmaf(a, ur[k], hr); hz = fmaf(a, uz[k], hz); hnn = fmaf(a, un[k], hnn);
    }
    const float r = 1.0f / (1.0f + expf(-(ir + hr)));
    const float z = 1.0f / (1.0f + expf(-(iz + hz)));
    const float cand = tanhf(inn + r * hnn);
    Wbt[j * IN_C + i] = f2bf((1.0f - z) * cand + z * w0row[j]);  // W[i][j] -> Wbt[j][i]
}

// ---------------- K2: packed histogram with rank capture ----------------
// pk[c] += (1<<32) | fix24(w); returned high word = this edge's rank at its dest.
__global__ __launch_bounds__(256) void hist_rank(const int* __restrict__ coli,
                                                 const float* __restrict__ ew,
                                                 unsigned long long* __restrict__ pk,
                                                 unsigned int* __restrict__ rank, int E) {
    const int e0 = (blockIdx.x * 256 + threadIdx.x) * 4;
    if (e0 + 3 < E) {
        const int4 c4 = *(const int4*)&coli[e0];
        const float4 w4 = *(const float4*)&ew[e0];
        const unsigned long long o0 = atomicAdd(&pk[c4.x], (1ull << 32) | (unsigned long long)(unsigned int)(w4.x * 16777216.0f));
        const unsigned long long o1 = atomicAdd(&pk[c4.y], (1ull << 32) | (unsigned long long)(unsigned int)(w4.y * 16777216.0f));
        const unsigned long long o2 = atomicAdd(&pk[c4.z], (1ull << 32) | (unsigned long long)(unsigned int)(w4.z * 16777216.0f));
        const unsigned long long o3 = atomicAdd(&pk[c4.w], (1ull << 32) | (unsigned long long)(unsigned int)(w4.w * 16777216.0f));
        uint4 rk;
        rk.x = (unsigned int)(o0 >> 32); rk.y = (unsigned int)(o1 >> 32);
        rk.z = (unsigned int)(o2 >> 32); rk.w = (unsigned int)(o3 >> 32);
        *(uint4*)&rank[e0] = rk;
    } else {
        for (int e = e0; e < E; ++e) {
            const unsigned long long o = atomicAdd(&pk[coli[e]],
                (1ull << 32) | (unsigned long long)(unsigned int)(ew[e] * 16777216.0f));
            rank[e] = (unsigned int)(o >> 32);
        }
    }
}

// ---------------- K3: scan counts -> rowptr (3 phases); scan1 also computes dinv ----------------
__global__ void scan1(const unsigned long long* __restrict__ pk, int* __restrict__ rowptr,
                      int* __restrict__ partials, float* __restrict__ dinv, int n) {
    __shared__ int s[256];
    const int t = threadIdx.x;
    const int i = blockIdx.x * 256 + t;
    const unsigned long long pv = (i < n) ? pk[i] : 0ull;
    if (i < n)
        dinv[i] = rsqrtf((float)(unsigned int)(pv & 0xffffffffull) * (1.0f / 16777216.0f) + 1.0f);
    s[t] = (int)(pv >> 32);
    __syncthreads();
    #pragma unroll
    for (int off = 1; off < 256; off <<= 1) {
        const int v = (t >= off) ? s[t - off] : 0;
        __syncthreads();
        s[t] += v;
        __syncthreads();
    }
    if (i < n) rowptr[i] = (t == 0) ? 0 : s[t - 1];
    if (t == 255) partials[blockIdx.x] = s[255];
}

__global__ void scan2(int* __restrict__ partials, int* __restrict__ rowptr, int nb, int n, int E) {
    __shared__ int s[512];
    const int t = threadIdx.x;
    s[t] = (t < nb) ? partials[t] : 0;
    __syncthreads();
    #pragma unroll
    for (int off = 1; off < 512; off <<= 1) {
        const int v = (t >= off) ? s[t - off] : 0;
        __syncthreads();
        s[t] += v;
        __syncthreads();
    }
    if (t < nb) partials[t] = (t == 0) ? 0 : s[t - 1];
    if (t == 0) rowptr[n] = E;
}

__global__ void scan3(int* __restrict__ rowptr, const int* __restrict__ partials, int n) {
    const int i = blockIdx.x * blockDim.x + threadIdx.x;
    if (i < n) rowptr[i] += partials[blockIdx.x];
}

// ---------------- K4: placement via rowptr + rank (NO atomics) ----------------
__global__ __launch_bounds__(256) void place(const int* __restrict__ rowi,
                                             const int* __restrict__ coli,
                                             const float* __restrict__ ew,
                                             const float* __restrict__ dinv,
                                             const int* __restrict__ rowptr,
                                             const unsigned int* __restrict__ rank,
                                             uint2* __restrict__ edge_sn, int E) {
    const int e0 = (blockIdx.x * 256 + threadIdx.x) * 4;
    if (e0 + 3 < E) {
        const int4 r4 = *(const int4*)&rowi[e0];
        const int4 c4 = *(const int4*)&coli[e0];
        const float4 w4 = *(const float4*)&ew[e0];
        const uint4 rk = *(const uint4*)&rank[e0];
        edge_sn[rowptr[c4.x] + rk.x] = make_uint2((unsigned)r4.x, __float_as_uint(dinv[r4.x] * w4.x * dinv[c4.x]));
        edge_sn[rowptr[c4.y] + rk.y] = make_uint2((unsigned)r4.y, __float_as_uint(dinv[r4.y] * w4.y * dinv[c4.y]));
        edge_sn[rowptr[c4.z] + rk.z] = make_uint2((unsigned)r4.z, __float_as_uint(dinv[r4.z] * w4.z * dinv[c4.z]));
        edge_sn[rowptr[c4.w] + rk.w] = make_uint2((unsigned)r4.w, __float_as_uint(dinv[r4.w] * w4.w * dinv[c4.w]));
    } else {
        for (int e = e0; e < E; ++e) {
            const int r = rowi[e], c = coli[e];
            edge_sn[rowptr[c] + rank[e]] = make_uint2((unsigned)r, __float_as_uint(dinv[r] * ew[e] * dinv[c]));
        }
    }
}

// ---------------- K5: h = bf16(x @ W) via MFMA ----------------
#define ALD 136  // 128 + 8 shorts pad
__global__ __launch_bounds__(256) void gemm_bf16(const float* __restrict__ x,
                                                 const unsigned short* __restrict__ Wbt,
                                                 unsigned short* __restrict__ hb, int n) {
    __shared__ unsigned short As[128 * ALD];
    __shared__ unsigned short Ws[128 * ALD];
    const int t = threadIdx.x;
    const size_t row0 = (size_t)blockIdx.x * 128;

    for (int idx = t; idx < 2048; idx += 256) {
        const int nn = idx >> 4, k8 = (idx & 15) * 8;
        *(uint4*)&Ws[nn * ALD + k8] = *(const uint4*)&Wbt[nn * IN_C + k8];
    }
    for (int idx = t; idx < 4096; idx += 256) {
        const int r = idx >> 5, c4 = (idx & 31) * 4;
        size_t row = row0 + r;
        if (row >= (size_t)n) row = (size_t)n - 1;
        const float4 v = *(const float4*)&x[row * IN_C + c4];
        ushort4 bb;
        bb.x = f2bf(v.x); bb.y = f2bf(v.y); bb.z = f2bf(v.z); bb.w = f2bf(v.w);
        *(ushort4*)&As[r * ALD + c4] = bb;
    }
    __syncthreads();

    const int w = t >> 6, lane = t & 63, ln = lane & 15, quad = lane >> 4;
    floatx4 acc[2][8];
    #pragma unroll
    for (int mt = 0; mt < 2; ++mt)
        #pragma unroll
        for (int nt = 0; nt < 8; ++nt)
            acc[mt][nt] = (floatx4){0.f, 0.f, 0.f, 0.f};

    #pragma unroll
    for (int k0 = 0; k0 < 128; k0 += 32) {
        const short8 a0 = *(const short8*)&As[(w * 32 + ln) * ALD + k0 + quad * 8];
        const short8 a1 = *(const short8*)&As[(w * 32 + 16 + ln) * ALD + k0 + quad * 8];
        #pragma unroll
        for (int nt = 0; nt < 8; ++nt) {
            const short8 bb = *(const short8*)&Ws[(nt * 16 + ln) * ALD + k0 + quad * 8];
            acc[0][nt] = __builtin_amdgcn_mfma_f32_16x16x32_bf16(a0, bb, acc[0][nt], 0, 0, 0);
            acc[1][nt] = __builtin_amdgcn_mfma_f32_16x16x32_bf16(a1, bb, acc[1][nt], 0, 0, 0);
        }
    }

    #pragma unroll
    for (int mt = 0; mt < 2; ++mt) {
        #pragma unroll
        for (int reg = 0; reg < 4; ++reg) {
            const size_t row = row0 + w * 32 + mt * 16 + quad * 4 + reg;
            if (row < (size_t)n) {
                #pragma unroll
                for (int nt = 0; nt < 8; ++nt)
                    hb[row * IN_C + nt * 16 + ln] = f2bf(acc[mt][nt][reg]);
            }
        }
    }
}

// ---------------- K6: fused gather + self-loop + ReLU + classifier ----------------
__global__ __launch_bounds__(256) void gather_classify(
        const unsigned short* __restrict__ hb, const float* __restrict__ dinv,
        const int* __restrict__ rowptr, const uint2* __restrict__ edge_sn,
        const float* __restrict__ cls_w, const float* __restrict__ cls_b,
        float* __restrict__ out, int n) {
    const int wid = __builtin_amdgcn_readfirstlane((blockIdx.x * blockDim.x + threadIdx.x) >> 6);
    const int lane = threadIdx.x & 63;
    if (wid >= n) return;

    const float dv = dinv[wid];
    unsigned int hv = *(const unsigned int*)&hb[(size_t)wid * IN_C + 2 * lane];
    float ax = dv * dv * __uint_as_float(hv << 16);
    float ay = dv * dv * __uint_as_float(hv & 0xffff0000u);

    const int e0 = rowptr[wid];
    const int e1 = rowptr[wid + 1];
    const int e1m1 = e1 - 1;
    for (int e = e0; e < e1; e += 8) {
        uint2 p[8];
        #pragma unroll
        for (int i = 0; i < 8; ++i) {
            const int idx = (e + i < e1) ? (e + i) : e1m1;
            p[i] = edge_sn[idx];
        }
        unsigned int hr[8];
        #pragma unroll
        for (int i = 0; i < 8; ++i)
            hr[i] = *(const unsigned int*)&hb[(size_t)p[i].x * IN_C + 2 * lane];
        #pragma unroll
        for (int i = 0; i < 8; ++i) {
            const float nm = (e + i < e1) ? __uint_as_float(p[i].y) : 0.0f;
            ax = fmaf(nm, __uint_as_float(hr[i] << 16), ax);
            ay = fmaf(nm, __uint_as_float(hr[i] & 0xffff0000u), ay);
        }
    }

    const float2 wv = *(const float2*)&cls_w[2 * lane];
    float sum = wv.x * fmaxf(ax, 0.0f) + wv.y * fmaxf(ay, 0.0f);
    #pragma unroll
    for (int off = 32; off > 0; off >>= 1) sum += __shfl_down(sum, off);
    if (lane == 0) out[wid] = sum + cls_b[0];
}

extern "C" void kernel_launch(void* const* d_in, const int* in_sizes, int n_in,
                              void* d_out, int out_size, void* d_ws, size_t ws_size,
                              hipStream_t stream) {
    const float* x    = (const float*)d_in[0];
    const int*   eidx = (const int*)d_in[1];   // [2, E] int32
    const float* ew   = (const float*)d_in[2];
    const float* W0   = (const float*)d_in[3];
    const float* Wih  = (const float*)d_in[4];
    const float* Whh  = (const float*)d_in[5];
    const float* bih  = (const float*)d_in[6];
    const float* bhh  = (const float*)d_in[7];
    const float* clsw = (const float*)d_in[8];
    const float* clsb = (const float*)d_in[9];
    float* out = (float*)d_out;

    const int n = in_sizes[0] / IN_C;   // 100000
    const int E = in_sizes[2];          // 600000
    const int* rowi = eidx;
    const int* coli = eidx + E;
    const int NB = (n + 255) / 256;     // <= 512

    // workspace layout (4-byte units from base)
    int* base = (int*)d_ws;
    unsigned long long* pk = (unsigned long long*)base;          // n u64 (8B aligned)
    float* dinv   = (float*)(base + 2 * (size_t)n);              // n
    int* rowptr   = base + 3 * (size_t)n;                        // n+1
    int* partials = base + 4 * (size_t)n + 4;                    // 512
    unsigned int* rank = (unsigned int*)(base + 4 * (size_t)n + 516);  // E
    size_t off = 4 * (size_t)n + 516 + (size_t)E;                // even -> 8B aligned
    uint2* edge_sn = (uint2*)(base + off);                       // E uint2
    unsigned short* Wbt = (unsigned short*)(base + off + 2 * (size_t)E);  // 16384 bf16
    unsigned short* hb  = Wbt + 16384;                           // n*128 bf16

    const int EB = (E + 1023) / 1024;  // 4 edges/thread blocks

    // 1. GRU weight evolution (writes bf16 W^T directly)
    evolve_w<<<dim3(IN_C), dim3(IN_C), 0, stream>>>(W0, Wih, Whh, bih, bhh, Wbt);
    // 2. packed histogram + rank
    hipMemsetAsync(pk, 0, (size_t)n * 8, stream);
    hist_rank<<<dim3(EB), dim3(256), 0, stream>>>(coli, ew, pk, rank, E);
    // 3. scan counts -> rowptr; dinv
    scan1<<<dim3(NB), dim3(256), 0, stream>>>(pk, rowptr, partials, dinv, n);
    scan2<<<dim3(1), dim3(512), 0, stream>>>(partials, rowptr, NB, n, E);
    scan3<<<dim3(NB), dim3(256), 0, stream>>>(rowptr, partials, n);
    // 4. placement (no atomics)
    place<<<dim3(EB), dim3(256), 0, stream>>>(rowi, coli, ew, dinv, rowptr, rank, edge_sn, E);
    // 5. h = bf16(x @ W) via MFMA
    gemm_bf16<<<dim3((n + 127) / 128), dim3(256), 0, stream>>>(x, Wbt, hb, n);
    // 6. fused gather + ReLU + classifier
    gather_classify<<<dim3((n + 3) / 4), dim3(256), 0, stream>>>(hb, dinv, rowptr, edge_sn,
                                                                 clsw, clsb, out, n);
}